// Round 1
// baseline (196.952 us; speedup 1.0000x reference)
//
#include <hip/hip_runtime.h>

#define B_ 128
#define T_ 256
#define C_ 512
#define H_ 512
// softmax scale * log2(e):  (1/sqrt(512)) * 1.44269504
#define CSCALE 0.063763824f

typedef _Float16 f16x8 __attribute__((ext_vector_type(8)));
typedef _Float16 f16x4 __attribute__((ext_vector_type(4)));
typedef float    f32x4 __attribute__((ext_vector_type(4)));

// async global->LDS, 16B per lane; LDS dest must be wave-uniform base (+lane*16)
__device__ __forceinline__ void gld16(const void* gsrc, void* ldst) {
  __builtin_amdgcn_global_load_lds(
      (__attribute__((address_space(1))) void*)gsrc,
      (__attribute__((address_space(3))) void*)ldst, 16, 0, 0);
}

// ---------------------------------------------------------------- convert
__global__ __launch_bounds__(256) void cvt_kernel(
    const float4* __restrict__ x, const float4* __restrict__ wq,
    const float4* __restrict__ wk, const float4* __restrict__ wv,
    f16x4* __restrict__ dst) {
  const int NX = (B_ * T_ * C_) / 4;   // 4,194,304
  const int NW = (H_ * C_) / 4;        // 65,536
  const int total = NX + 3 * NW;
  int gid = blockIdx.x * 256 + threadIdx.x;
  int gsz = gridDim.x * 256;
  for (int i = gid; i < total; i += gsz) {
    float4 f;
    if (i < NX)            f = x[i];
    else if (i < NX + NW)  f = wq[i - NX];
    else if (i < NX + 2*NW) f = wk[i - NX - NW];
    else                   f = wv[i - NX - 2*NW];
    f16x4 u = {(_Float16)f.x, (_Float16)f.y, (_Float16)f.z, (_Float16)f.w};
    dst[i] = u;
  }
}

// ---------------------------------------------------------------- QKV proj
// gemm_bt: out[m][n] = sum_k A[m][k] * W[n][k];  m97 structure (128x128, BK=32)
// z=0 -> q [B*T, H]; z=1 -> k [B*T, H]; z=2 -> v^T [B, H, T]
__global__ __launch_bounds__(256) void proj_kernel(
    const _Float16* __restrict__ xh, const _Float16* __restrict__ wh,
    _Float16* __restrict__ qh, _Float16* __restrict__ kh,
    _Float16* __restrict__ vth) {
  __shared__ _Float16 As[128 * 32];  // 8 KB, row-major [128][32]
  __shared__ _Float16 Bs[128 * 32];  // 8 KB

  const int tid  = threadIdx.x;
  const int lane = tid & 63;
  const int wave = tid >> 6;
  const int lr = lane & 15, lk = lane >> 4;
  const int m0 = blockIdx.x * 128;
  const int n0 = blockIdx.y * 128;
  const int z  = blockIdx.z;
  const _Float16* wz = wh + z * (H_ * C_);

  const int wm = (wave >> 1) * 64;
  const int wn = (wave & 1) * 64;

  f32x4 acc[4][4];
#pragma unroll
  for (int i = 0; i < 4; ++i)
#pragma unroll
    for (int j = 0; j < 4; ++j) acc[i][j] = {0.f, 0.f, 0.f, 0.f};

  // staging: thread t covers row = i*64 + (t>>2), col = (t&3)*8 (8 f16 = 16B)
  const int srow = tid >> 2, scol = (tid & 3) * 8;
  const _Float16* aSrc = xh + (m0 + srow) * C_ + scol;
  const _Float16* bSrc = wz + (n0 + srow) * C_ + scol;

  for (int k0 = 0; k0 < C_; k0 += 32) {
    __syncthreads();  // previous compute done reading LDS
#pragma unroll
    for (int i = 0; i < 2; ++i) {
      gld16((const void*)(aSrc + i * 64 * C_ + k0), (void*)&As[i * 2048 + wave * 512]);
      gld16((const void*)(bSrc + i * 64 * C_ + k0), (void*)&Bs[i * 2048 + wave * 512]);
    }
    __syncthreads();  // staging drained (vmcnt(0) at barrier)

    f16x8 a[4], b[4];
#pragma unroll
    for (int mi = 0; mi < 4; ++mi)
      a[mi] = *(const f16x8*)&As[(wm + mi * 16 + lr) * 32 + lk * 8];
#pragma unroll
    for (int ni = 0; ni < 4; ++ni)
      b[ni] = *(const f16x8*)&Bs[(wn + ni * 16 + lr) * 32 + lk * 8];
#pragma unroll
    for (int mi = 0; mi < 4; ++mi)
#pragma unroll
      for (int ni = 0; ni < 4; ++ni)
        acc[mi][ni] = __builtin_amdgcn_mfma_f32_16x16x32_f16(a[mi], b[ni], acc[mi][ni], 0, 0, 0);
  }

  // epilogue. D layout: col = lane&15, row = (lane>>4)*4 + r   [measured m89/m91]
  if (z < 2) {
    _Float16* out = (z == 0) ? qh : kh;
#pragma unroll
    for (int mi = 0; mi < 4; ++mi) {
      int mbase = m0 + wm + mi * 16 + lk * 4;
#pragma unroll
      for (int ni = 0; ni < 4; ++ni) {
        int n = n0 + wn + ni * 16 + lr;
#pragma unroll
        for (int r = 0; r < 4; ++r)
          out[(mbase + r) * H_ + n] = (_Float16)acc[mi][ni][r];
      }
    }
  } else {
    // v^T[b][h][t]; r=0..3 are consecutive t -> pack 8B store
#pragma unroll
    for (int mi = 0; mi < 4; ++mi) {
      int mbase = m0 + wm + mi * 16 + lk * 4;
      int bb = mbase >> 8, tt = mbase & 255;
#pragma unroll
      for (int ni = 0; ni < 4; ++ni) {
        int n = n0 + wn + ni * 16 + lr;
        f16x4 u = {(_Float16)acc[mi][ni][0], (_Float16)acc[mi][ni][1],
                   (_Float16)acc[mi][ni][2], (_Float16)acc[mi][ni][3]};
        *(f16x4*)&vth[bb * (H_ * T_) + n * T_ + tt] = u;
      }
    }
  }
}

// ---------------------------------------------------------------- attention
// grid (4, 128): blockIdx.x = q-tile (QBLK=64), blockIdx.y = batch.
// 4 waves x 16 q-rows. KVBLK=32. LDS: Ks 32KB + Vs 32KB = 64KB exactly;
// P-transpose scratch aliases first 4KB of Ks (dead between barriers).
__global__ __launch_bounds__(256, 2) void attn_kernel(
    const _Float16* __restrict__ qh, const _Float16* __restrict__ kh,
    const _Float16* __restrict__ vth, float* __restrict__ dout) {
  // Ks: 2048 chunks of 8 f16: chunk(hb=0..63, kv=0..31) at [hb*32+kv]
  //     content = K[kv0+kv][hb*8 .. hb*8+7]
  __shared__ _Float16 Ks[16384];
  // Vs: 2048 chunks: chunk(tb=0..3, h=0..511) at [tb*512+h]
  //     content = v^T[h][kv0+tb*8 .. +7]  (= V[tk][h] K-major)
  __shared__ _Float16 Vs[16384];

  const int tid  = threadIdx.x;
  const int lane = tid & 63;
  const int wq   = tid >> 6;
  const int lr = lane & 15, lk = lane >> 4;
  const int qt = blockIdx.x;   // 0..3
  const int b  = blockIdx.y;   // 0..127
  const int q0 = qt * 64;
  const int nkv = (qt + 1) * 2;

  // hoist Q fragments: row = lr (within wave's 16 rows), k covered by (f, lk)
  f16x8 qf[16];
  const _Float16* qrow = qh + (b * T_ + q0 + wq * 16 + lr) * H_;
#pragma unroll
  for (int f = 0; f < 16; ++f) qf[f] = *(const f16x8*)&qrow[f * 32 + lk * 8];

  f32x4 o[32];
#pragma unroll
  for (int i = 0; i < 32; ++i) o[i] = {0.f, 0.f, 0.f, 0.f};
  float m[4], l[4];
#pragma unroll
  for (int r = 0; r < 4; ++r) { m[r] = -1e30f; l[r] = 0.f; }

  for (int kvt = 0; kvt < nkv; ++kvt) {
    const int kv0 = kvt * 32;
    __syncthreads();  // everyone done reading Ks/Vs (and P scratch)
#pragma unroll
    for (int i = 0; i < 8; ++i) {
      int c = i * 256 + tid;
      {  // K chunk: hb = c>>5, kv = c&31
        int hb = c >> 5, kv = c & 31;
        gld16((const void*)(kh + (b * T_ + kv0 + kv) * H_ + hb * 8),
              (void*)&Ks[i * 2048 + wq * 512]);
      }
      {  // V chunk: tb = c>>9, h = c&511
        int tb = c >> 9, h = c & 511;
        gld16((const void*)(vth + (b * H_ + h) * T_ + kv0 + tb * 8),
              (void*)&Vs[i * 2048 + wq * 512]);
      }
    }
    __syncthreads();  // staging drained

    // ---- QK^T: S[16q x 32kv], K-dim = H = 512
    f32x4 s0 = {0.f, 0.f, 0.f, 0.f}, s1 = {0.f, 0.f, 0.f, 0.f};
#pragma unroll
    for (int ks = 0; ks < 16; ++ks) {
      f16x8 b0 = *(const f16x8*)&Ks[((ks * 4 + lk) * 32 + lr) * 8];
      f16x8 b1 = *(const f16x8*)&Ks[((ks * 4 + lk) * 32 + 16 + lr) * 8];
      s0 = __builtin_amdgcn_mfma_f32_16x16x32_f16(qf[ks], b0, s0, 0, 0, 0);
      s1 = __builtin_amdgcn_mfma_f32_16x16x32_f16(qf[ks], b1, s1, 0, 0, 0);
    }

    // ---- causal mask + row max (rows live in (lk, r); cols across lr, ni)
    float p0[4], p1[4], rm[4];
    const int rowb = q0 + wq * 16 + lk * 4;
#pragma unroll
    for (int r = 0; r < 4; ++r) {
      float v0 = (kv0 + lr      > rowb + r) ? -1e30f : s0[r];
      float v1 = (kv0 + 16 + lr > rowb + r) ? -1e30f : s1[r];
      s0[r] = v0; s1[r] = v1;
      rm[r] = fmaxf(v0, v1);
    }
#pragma unroll
    for (int off = 1; off < 16; off <<= 1)
#pragma unroll
      for (int r = 0; r < 4; ++r) rm[r] = fmaxf(rm[r], __shfl_xor(rm[r], off, 64));

    // ---- defer-max (T13): only rescale when max grew > 64 raw (~e^2.8 headroom)
    bool need = false;
#pragma unroll
    for (int r = 0; r < 4; ++r) need = need || (rm[r] > m[r] + 64.f);
    if (__any(need)) {
#pragma unroll
      for (int r = 0; r < 4; ++r) {
        float mn = fmaxf(m[r], rm[r]);
        float al = __builtin_amdgcn_exp2f((m[r] - mn) * CSCALE);
        m[r] = mn; l[r] *= al;
#pragma unroll
        for (int hf = 0; hf < 32; ++hf) o[hf][r] *= al;
      }
    }

    float rs[4];
#pragma unroll
    for (int r = 0; r < 4; ++r) {
      p0[r] = __builtin_amdgcn_exp2f((s0[r] - m[r]) * CSCALE);
      p1[r] = __builtin_amdgcn_exp2f((s1[r] - m[r]) * CSCALE);
      rs[r] = p0[r] + p1[r];
    }
#pragma unroll
    for (int off = 1; off < 16; off <<= 1)
#pragma unroll
      for (int r = 0; r < 4; ++r) rs[r] += __shfl_xor(rs[r], off, 64);
#pragma unroll
    for (int r = 0; r < 4; ++r) l[r] += rs[r];

    __syncthreads();  // all waves done reading Ks before P overwrites it

    // ---- P transpose through per-wave LDS scratch (aliases Ks[wq*512..])
    _Float16* Ps = &Ks[wq * 512];  // [16 q][32 tk] row-major
#pragma unroll
    for (int r = 0; r < 4; ++r) {
      Ps[(lk * 4 + r) * 32 + lr]      = (_Float16)p0[r];
      Ps[(lk * 4 + r) * 32 + 16 + lr] = (_Float16)p1[r];
    }
    f16x8 pa = *(const f16x8*)&Ps[lr * 32 + lk * 8];  // A-frag: row=lr, k=lk*8+j

    // ---- PV: o[16q x 512h] += P[16x32] * V[32x512]
#pragma unroll
    for (int hf = 0; hf < 32; ++hf) {
      f16x8 vb = *(const f16x8*)&Vs[(lk * 512 + hf * 16 + lr) * 8];
      o[hf] = __builtin_amdgcn_mfma_f32_16x16x32_f16(pa, vb, o[hf], 0, 0, 0);
    }
  }

  // ---- normalize + store fp32
  float linv[4];
#pragma unroll
  for (int r = 0; r < 4; ++r) linv[r] = 1.0f / l[r];
  float* orow = dout + (size_t)(b * T_ + q0 + wq * 16 + lk * 4) * H_;
#pragma unroll
  for (int hf = 0; hf < 32; ++hf)
#pragma unroll
    for (int r = 0; r < 4; ++r)
      orow[(size_t)r * H_ + hf * 16 + lr] = o[hf][r] * linv[r];
}

// ---------------------------------------------------------------- launch
extern "C" void kernel_launch(void* const* d_in, const int* in_sizes, int n_in,
                              void* d_out, int out_size, void* d_ws, size_t ws_size,
                              hipStream_t stream) {
  const size_t NXE = (size_t)B_ * T_ * C_;   // 16,777,216
  const size_t NWE = (size_t)3 * H_ * C_;    // 786,432
  const size_t NQE = (size_t)B_ * T_ * H_;   // 16,777,216
  const size_t need = (NXE + NWE + 3 * NQE) * sizeof(_Float16);  // 135,790,592 B
  if (ws_size < need) return;  // loud failure (absmax = max|ref|) -> ws too small

  const float* x  = (const float*)d_in[0];
  const float* wq = (const float*)d_in[1];
  const float* wk = (const float*)d_in[2];
  const float* wv = (const float*)d_in[3];

  _Float16* xh  = (_Float16*)d_ws;
  _Float16* wh  = xh + NXE;
  _Float16* qh  = wh + NWE;
  _Float16* kh  = qh + NQE;
  _Float16* vth = kh + NQE;

  cvt_kernel<<<2048, 256, 0, stream>>>((const float4*)x, (const float4*)wq,
                                       (const float4*)wk, (const float4*)wv,
                                       (f16x4*)xh);
  proj_kernel<<<dim3(256, 4, 3), dim3(256), 0, stream>>>(xh, wh, qh, kh, vth);
  attn_kernel<<<dim3(4, 128), dim3(256), 0, stream>>>(qh, kh, vth, (float*)d_out);
}